// Round 12
// baseline (219.034 us; speedup 1.0000x reference)
//
#include <hip/hip_runtime.h>
#include <hip/hip_bf16.h>

#define NN 8192
#define IN_F 256
#define OF 128

typedef float  f32x4   __attribute__((ext_vector_type(4)));
typedef short  short4v __attribute__((ext_vector_type(4)));
typedef short  short8v __attribute__((ext_vector_type(8)));
typedef int    int4v   __attribute__((ext_vector_type(4)));

__device__ __forceinline__ unsigned short bf16_bits(float x) {
    __bf16 b = (__bf16)x;
    return __builtin_bit_cast(unsigned short, b);
}

__device__ __forceinline__ f32x4 mfma16(short4v a, short4v b, f32x4 c) {
#if __has_builtin(__builtin_amdgcn_mfma_f32_16x16x16bf16_1k)
    return __builtin_amdgcn_mfma_f32_16x16x16bf16_1k(a, b, c, 0, 0, 0);
#else
    asm("v_mfma_f32_16x16x16_bf16 %0, %1, %2, %0" : "+v"(c) : "v"(a), "v"(b));
    return c;
#endif
}

// async global->LDS, 16B per lane; LDS dest = wave-uniform base + lane*16
__device__ __forceinline__ void gload_lds16(const void* gsrc, void* lds) {
    __builtin_amdgcn_global_load_lds(
        (const __attribute__((address_space(1))) int*)gsrc,
        (__attribute__((address_space(3))) int*)lds, 16, 0, 0);
}

// ---------------------------------------------------------------------------
// Kernel A: h = X @ W (f32, LDS-staged W).  Emits HtB in MFMA-B-fragment
// order (verified R3+):  for h[j][f]:
//   kt=j>>4, g=(j>>2)&3, e=j&3, np=f>>5, o=(f>>4)&1, c=f&15
//   short index = ((kt*4+np)*64 + g*16 + c)*8 + o*4 + e
// Also f_src = h.a[:OF], f_dst = h.a[OF:].
// ---------------------------------------------------------------------------
__global__ __launch_bounds__(256) void gat_prep(
    const float* __restrict__ X, const float* __restrict__ W,
    const float* __restrict__ a, unsigned short* __restrict__ HtB,
    float* __restrict__ f_src, float* __restrict__ f_dst)
{
    __shared__ float Wlds[IN_F * OF];   // 128 KiB
    __shared__ float red_s[32][8];
    __shared__ float red_d[32][8];

    const int t = threadIdx.x;
    {
        const f32x4* Wv = (const f32x4*)W;
        f32x4*       Wl = (f32x4*)Wlds;
        #pragma unroll
        for (int c = 0; c < 32; ++c) Wl[c * 256 + t] = Wv[c * 256 + t];
    }
    __syncthreads();

    const int row = t & 31;
    const int sub = t >> 5;
    const int i   = blockIdx.x * 32 + row;

    f32x4 acc[4] = {};
    const float* xrow = X + (size_t)i * IN_F;

    #pragma unroll 4
    for (int kk = 0; kk < IN_F; kk += 4) {
        f32x4 xv = *(const f32x4*)(xrow + kk);
        #pragma unroll
        for (int e = 0; e < 4; ++e) {
            const f32x4* wr = (const f32x4*)(Wlds + (kk + e) * OF + sub * 16);
            float xs = xv[e];
            #pragma unroll
            for (int c4 = 0; c4 < 4; ++c4) acc[c4] += xs * wr[c4];
        }
    }

    const int kt = i >> 4;
    const int gq = (i >> 2) & 3;
    const int eq = i & 3;
    const int np = sub >> 1;
    const int oo = sub & 1;

    float ps = 0.f, pd = 0.f;
    #pragma unroll
    for (int c4 = 0; c4 < 4; ++c4) {
        #pragma unroll
        for (int e = 0; e < 4; ++e) {
            float v = acc[c4][e];
            int   c = c4 * 4 + e;
            ps += v * a[sub * 16 + c];
            pd += v * a[OF + sub * 16 + c];
            HtB[(size_t)(((kt * 4 + np) * 64) + gq * 16 + c) * 8 + oo * 4 + eq]
                = bf16_bits(v);
        }
    }
    red_s[row][sub] = ps;
    red_d[row][sub] = pd;
    __syncthreads();
    if (t < 32) {
        float s = 0.f;
        #pragma unroll
        for (int s8 = 0; s8 < 8; ++s8) s += red_s[t][s8];
        f_src[blockIdx.x * 32 + t] = s;
    } else if (t < 64) {
        const int r2 = t - 32;
        float s = 0.f;
        #pragma unroll
        for (int s8 = 0; s8 < 8; ++s8) s += red_d[r2][s8];
        f_dst[blockIdx.x * 32 + r2] = s;
    }
}

// ---------------------------------------------------------------------------
// Kernel B v12 (gat_fat2): staged-B + fat-rows + full occupancy.
// Grid = 256 row-tiles x 2 k-splits = 512 blocks (2/CU) x 512 threads.
// Block = 32 rows, K-range = ks*4096..+4095 (256 kt = 32 supersteps x 8 kt).
// Wave (rw = w&1, fw = w>>2? no: w&1 rows, w>>1 feats):
//   rw in [0,2): rows rw*16..+16;  fw in [0,4): feats fw*32..+32.
// All waves share each kt: B staged 32KB/superstep via global_load_lds
// (double-buffered; linear copy since HtB is already fragment-ordered).
// One ds_read_b128 per kt per wave covers its 2 feature fragments.
// adj: 4-deep register queue (issue kt+4, consume kt) -> the vmcnt(0) drain
// at each superstep barrier COMPLETES in-flight adj instead of stalling.
// Partial 32x128 tiles + rowsums to ws; gat_finish combines the 2 k-splits.
// ---------------------------------------------------------------------------
__global__ __launch_bounds__(512, 4) void gat_fat2(
    const int* __restrict__ adj, const short8v* __restrict__ htv,
    const float* __restrict__ f_src, const float* __restrict__ f_dst,
    float* __restrict__ part, float* __restrict__ rsPart)
{
    __shared__ __align__(16) char smem[65536 + 256];
    // [0,65536): 2 x 32KiB B double-buffer; epilogue reuses [0,16KiB) as slab
    // [65536, +128): rsum[2][16]

    const int tid  = threadIdx.x;
    const int w    = tid >> 6;
    const int lane = tid & 63;
    const int rw   = w & 1;
    const int fw   = w >> 1;
    const int r    = lane & 15;
    const int g    = lane >> 4;
    const int rt2  = blockIdx.x >> 1;
    const int ks   = blockIdx.x & 1;
    const int rowbase = rt2 * 32;
    const int row  = rowbase + rw * 16 + r;

    const float fsrc_r = f_src[row];
    const int*   aptr = adj + (size_t)row * NN + ks * 4096 + g * 4;
    const float* fptr = f_dst + ks * 4096 + g * 4;
    const char*  gB   = (const char*)htv + ((size_t)ks * 256 * 256) * 16;

    f32x4 acc[2] = {};
    float psum = 0.f;

    // ---- prologue ----
    // stage superstep 0 into buf 0 (4 x 16B per thread, linear copy)
    #pragma unroll
    for (int u = 0; u < 4; ++u)
        gload_lds16(gB + (size_t)(u * 512 + tid) * 16,
                    smem + u * 8192 + (size_t)tid * 16);

    // adj queue (4-deep), f_dst queue (2-deep); i = kt index in [0,256)
    int4v q[4];
    #pragma unroll
    for (int j = 0; j < 4; ++j) q[j] = *(const int4v*)(aptr + j * 16);
    f32x4 fq0 = *(const f32x4*)(fptr + 0 * 16);
    f32x4 fq1 = *(const f32x4*)(fptr + 1 * 16);

    int buf = 0;
    for (int ss = 0; ss < 32; ++ss) {
        __syncthreads();   // stage(ss) complete; previous reads of buf done

        // stage superstep ss+1 into the other buffer
        if (ss + 1 < 32) {
            const size_t sb = (size_t)(ss + 1) * 2048 * 16;
            #pragma unroll
            for (int u = 0; u < 4; ++u)
                gload_lds16(gB + sb + (size_t)(u * 512 + tid) * 16,
                            smem + (buf ^ 1) * 32768 + u * 8192 + (size_t)tid * 16);
        }

        #pragma unroll
        for (int ktl = 0; ktl < 8; ++ktl) {
            const int i = ss * 8 + ktl;

            // consume queues, then refill (wrap keeps addresses valid)
            const int4v ac = q[i & 3];
            q[i & 3] = *(const int4v*)(aptr + ((i + 4) & 255) * 16);
            const f32x4 fc = (i & 1) ? fq1 : fq0;
            if (i & 1) fq1 = *(const f32x4*)(fptr + ((i + 2) & 255) * 16);
            else       fq0 = *(const f32x4*)(fptr + ((i + 2) & 255) * 16);

            // this wave's B fragment pair: one 16B LDS read
            const short8v bv = *(const short8v*)(
                smem + buf * 32768 + (size_t)((ktl * 4 + fw) * 64 + lane) * 16);

            float p[4];
            #pragma unroll
            for (int e = 0; e < 4; ++e) {
                float s = fsrc_r + fc[e];
                s = s > 0.f ? s : 0.2f * s;          // leaky_relu
                p[e] = (ac[e] != 0) ? __expf(s) : 0.f;
            }
            psum += (p[0] + p[1]) + (p[2] + p[3]);
            const short4v af = { (short)bf16_bits(p[0]), (short)bf16_bits(p[1]),
                                 (short)bf16_bits(p[2]), (short)bf16_bits(p[3]) };

            acc[0] = mfma16(af, __builtin_shufflevector(bv, bv, 0, 1, 2, 3), acc[0]);
            acc[1] = mfma16(af, __builtin_shufflevector(bv, bv, 4, 5, 6, 7), acc[1]);
        }
        buf ^= 1;
    }

    // rowsum partials (all fw waves computed identical psum; fw==0 writes)
    psum += __shfl_xor(psum, 16, 64);
    psum += __shfl_xor(psum, 32, 64);
    float* rsum = (float*)(smem + 65536);   // [2][16]
    __syncthreads();   // all buf reads done; smem reusable
    if (fw == 0 && lane < 16) rsum[rw * 16 + lane] = psum;

    // assemble 32x128 f32 tile in slab (waves own disjoint 16x32 chunks)
    float* slab = (float*)smem;             // [32][OF], 16 KiB (buf0 region)
    #pragma unroll
    for (int oo = 0; oo < 2; ++oo)
        #pragma unroll
        for (int qq = 0; qq < 4; ++qq)
            slab[(rw * 16 + g * 4 + qq) * OF + fw * 32 + oo * 16 + r] = acc[oo][qq];
    __syncthreads();

    // write partial tile (coalesced) + rowsum partials
    float* pb = part + ((size_t)ks * NN + rowbase) * OF;
    #pragma unroll
    for (int c = 0; c < 2; ++c) {
        const int idx = tid * 2 + c;        // f32x4 index into 32x128 tile
        *(f32x4*)(pb + (size_t)idx * 4) = *(const f32x4*)&slab[idx * 4];
    }
    if (tid < 32) rsPart[(size_t)ks * NN + rowbase + tid] = rsum[tid];
}

// ---------------------------------------------------------------------------
// Finish: out = relu( (part0+part1) / (rs0+rs1) ).  512 blocks x 512 threads.
// ---------------------------------------------------------------------------
__global__ __launch_bounds__(512) void gat_finish(
    const float* __restrict__ part, const float* __restrict__ rsPart,
    float* __restrict__ out)
{
    const int tg  = blockIdx.x * 512 + threadIdx.x;   // f32x4 index
    const int row = tg >> 5;

    f32x4 v = *(const f32x4*)(part + (size_t)tg * 4);
    v += *(const f32x4*)(part + (size_t)NN * OF + (size_t)tg * 4);

    const float den = rsPart[row] + rsPart[NN + row];
    const float inv = 1.0f / den;
    f32x4 o = v * inv;
    #pragma unroll
    for (int e = 0; e < 4; ++e) o[e] = fmaxf(o[e], 0.f);
    *(f32x4*)(out + (size_t)tg * 4) = o;
}

extern "C" void kernel_launch(void* const* d_in, const int* in_sizes, int n_in,
                              void* d_out, int out_size, void* d_ws, size_t ws_size,
                              hipStream_t stream) {
    const float* X   = (const float*)d_in[0];
    const int*   adj = (const int*)d_in[1];
    const float* W   = (const float*)d_in[2];
    const float* a   = (const float*)d_in[3];
    float* out = (float*)d_out;

    char* ws = (char*)d_ws;
    unsigned short* HtB    = (unsigned short*)ws;                  // 2 MiB
    float*          f_src  = (float*)(ws + 2097152);               // 32 KiB
    float*          f_dst  = (float*)(ws + 2097152 + 32768);       // 32 KiB
    float*          rsPart = (float*)(ws + 2097152 + 65536);       // 64 KiB
    float*          part   = (float*)(ws + 2097152 + 131072);      // 8 MiB

    gat_prep<<<NN / 32, 256, 0, stream>>>(X, W, a, HtB, f_src, f_dst);
    gat_fat2<<<512, 512, 0, stream>>>(adj, (const short8v*)HtB,
                                      f_src, f_dst, part, rsPart);
    gat_finish<<<512, 512, 0, stream>>>(part, rsPart, out);
}

// Round 13
// 151.282 us; speedup vs baseline: 1.4479x; 1.4479x over previous
//
#include <hip/hip_runtime.h>
#include <hip/hip_bf16.h>

#define NN 8192
#define IN_F 256
#define OF 128

typedef float  f32x4   __attribute__((ext_vector_type(4)));
typedef short  short4v __attribute__((ext_vector_type(4)));
typedef short  short8v __attribute__((ext_vector_type(8)));
typedef int    int4v   __attribute__((ext_vector_type(4)));
typedef unsigned long long u64;

__device__ __forceinline__ unsigned short bf16_bits(float x) {
    __bf16 b = (__bf16)x;
    return __builtin_bit_cast(unsigned short, b);
}

__device__ __forceinline__ f32x4 mfma16(short4v a, short4v b, f32x4 c) {
#if __has_builtin(__builtin_amdgcn_mfma_f32_16x16x16bf16_1k)
    return __builtin_amdgcn_mfma_f32_16x16x16bf16_1k(a, b, c, 0, 0, 0);
#else
    asm("v_mfma_f32_16x16x16_bf16 %0, %1, %2, %0" : "+v"(c) : "v"(a), "v"(b));
    return c;
#endif
}

// async global->LDS, 16B per lane; LDS dest = wave-uniform base + lane*16
__device__ __forceinline__ void gload_lds16(const void* gsrc, void* lds) {
    __builtin_amdgcn_global_load_lds(
        (const __attribute__((address_space(1))) int*)gsrc,
        (__attribute__((address_space(3))) int*)lds, 16, 0, 0);
}

// ---------------------------------------------------------------------------
// Kernel A: h = X @ W (f32, LDS-staged W).  Emits HtB in MFMA-B-fragment
// order (verified R3+).  Also f_src = h.a[:OF], f_dst = h.a[OF:].
// ---------------------------------------------------------------------------
__global__ __launch_bounds__(256) void gat_prep(
    const float* __restrict__ X, const float* __restrict__ W,
    const float* __restrict__ a, unsigned short* __restrict__ HtB,
    float* __restrict__ f_src, float* __restrict__ f_dst)
{
    __shared__ float Wlds[IN_F * OF];   // 128 KiB
    __shared__ float red_s[32][8];
    __shared__ float red_d[32][8];

    const int t = threadIdx.x;
    {
        const f32x4* Wv = (const f32x4*)W;
        f32x4*       Wl = (f32x4*)Wlds;
        #pragma unroll
        for (int c = 0; c < 32; ++c) Wl[c * 256 + t] = Wv[c * 256 + t];
    }
    __syncthreads();

    const int row = t & 31;
    const int sub = t >> 5;
    const int i   = blockIdx.x * 32 + row;

    f32x4 acc[4] = {};
    const float* xrow = X + (size_t)i * IN_F;

    #pragma unroll 4
    for (int kk = 0; kk < IN_F; kk += 4) {
        f32x4 xv = *(const f32x4*)(xrow + kk);
        #pragma unroll
        for (int e = 0; e < 4; ++e) {
            const f32x4* wr = (const f32x4*)(Wlds + (kk + e) * OF + sub * 16);
            float xs = xv[e];
            #pragma unroll
            for (int c4 = 0; c4 < 4; ++c4) acc[c4] += xs * wr[c4];
        }
    }

    const int kt = i >> 4;
    const int gq = (i >> 2) & 3;
    const int eq = i & 3;
    const int np = sub >> 1;
    const int oo = sub & 1;

    float ps = 0.f, pd = 0.f;
    #pragma unroll
    for (int c4 = 0; c4 < 4; ++c4) {
        #pragma unroll
        for (int e = 0; e < 4; ++e) {
            float v = acc[c4][e];
            int   c = c4 * 4 + e;
            ps += v * a[sub * 16 + c];
            pd += v * a[OF + sub * 16 + c];
            HtB[(size_t)(((kt * 4 + np) * 64) + gq * 16 + c) * 8 + oo * 4 + eq]
                = bf16_bits(v);
        }
    }
    red_s[row][sub] = ps;
    red_d[row][sub] = pd;
    __syncthreads();
    if (t < 32) {
        float s = 0.f;
        #pragma unroll
        for (int s8 = 0; s8 < 8; ++s8) s += red_s[t][s8];
        f_src[blockIdx.x * 32 + t] = s;
    } else if (t < 64) {
        const int r2 = t - 32;
        float s = 0.f;
        #pragma unroll
        for (int s8 = 0; s8 < 8; ++s8) s += red_d[r2][s8];
        f_dst[blockIdx.x * 32 + r2] = s;
    }
}

// ---------------------------------------------------------------------------
// gat_pack: adj (int32 0/1, 256 MB) -> bitmask (8 MB).  Pure stream at
// fill-rate (verified structure, R8).  bits viewed as ushort[8192][512]:
// ushort[i][kt] bit (g*4+e) = adj[i][kt*16+g*4+e].
// ---------------------------------------------------------------------------
__global__ __launch_bounds__(256) void gat_pack(
    const int* __restrict__ adj, u64* __restrict__ bits)
{
    const int tid  = threadIdx.x;
    const int wave = tid >> 6;
    const int lane = tid & 63;
    const int row  = blockIdx.x * 4 + wave;

    const int* arow = adj + (size_t)row * NN + lane;
    u64* brow = bits + (size_t)row * (NN / 64);

    #pragma unroll 2
    for (int it = 0; it < 32; ++it) {
        const int c0 = it * 256;
        const int v0 = arow[c0];
        const int v1 = arow[c0 + 64];
        const int v2 = arow[c0 + 128];
        const int v3 = arow[c0 + 192];
        const u64 m0 = __ballot(v0 != 0);
        const u64 m1 = __ballot(v1 != 0);
        const u64 m2 = __ballot(v2 != 0);
        const u64 m3 = __ballot(v3 != 0);
        if (lane == 0) {
            brow[it * 4 + 0] = m0;
            brow[it * 4 + 1] = m1;
            brow[it * 4 + 2] = m2;
            brow[it * 4 + 3] = m3;
        }
    }
}

// ---------------------------------------------------------------------------
// gat_row (v13): row-owning waves + block-shared LDS-staged B + bit-mask adj.
// Grid = 64 row-blocks x 8 k-splits = 512 blocks (2/CU) x 512 threads.
// Block = 128 rows; wave w owns rows rowbase+w*16..+15 (disjoint -> no exp
// duplication, no cross-wave reduction).  K-range = ks*1024..+1023 (64 kt);
// 8 supersteps x 8 kt; B slab (32 KB) staged via global_load_lds, double-
// buffered, SHARED by all 8 waves -> HtB traffic = 128 MB total, 8 barrier
// drains per block only.  A-side: bits ushort (L1) + f_dst f32x4 (L1).
// Per iter/wave: 1 ushort + 1 f32x4 + 4 ds_read_b128 + 4 exps + 8 MFMA.
// Partials (16x128 f32 per wave) written direct; finish combines 8 k-splits.
// ---------------------------------------------------------------------------
__global__ __launch_bounds__(512, 4) void gat_row(
    const unsigned short* __restrict__ bits, const char* __restrict__ htb,
    const float* __restrict__ f_src, const float* __restrict__ f_dst,
    float* __restrict__ part, float* __restrict__ rsPart)
{
    __shared__ __align__(16) char smem[65536];   // 2 x 32KiB B dbuf; epilogue lt

    const int tid  = threadIdx.x;
    const int w    = tid >> 6;
    const int lane = tid & 63;
    const int r    = lane & 15;
    const int g    = lane >> 4;
    const int ms   = blockIdx.x >> 3;
    const int ks   = blockIdx.x & 7;
    const int rowbase = ms * 128;
    const int row  = rowbase + w * 16 + r;
    const int ktbase = ks * 64;

    const float fsrc_r = f_src[row];
    const unsigned short* bptr = bits + (size_t)row * (NN / 16);
    const char* gB = htb + (size_t)ktbase * 4096;   // 4KB per kt

    f32x4 acc[8] = {};
    float psum = 0.f;

    // prologue: stage superstep 0 into buf 0 (32KB, linear)
    #pragma unroll
    for (int u = 0; u < 4; ++u)
        gload_lds16(gB + (size_t)(u * 512 + tid) * 16,
                    smem + (size_t)(u * 512 + tid) * 16);

    int buf = 0;
    for (int ss = 0; ss < 8; ++ss) {
        __syncthreads();   // stage(ss) resident (vmcnt drain); buf^1 free

        if (ss + 1 < 8) {
            const char* gs = gB + (size_t)(ss + 1) * 32768;
            #pragma unroll
            for (int u = 0; u < 4; ++u)
                gload_lds16(gs + (size_t)(u * 512 + tid) * 16,
                            smem + (buf ^ 1) * 32768 + (size_t)(u * 512 + tid) * 16);
        }

        #pragma unroll
        for (int ktl = 0; ktl < 8; ++ktl) {
            const int kt = ktbase + ss * 8 + ktl;

            const unsigned int b16 = bptr[kt];
            const f32x4 fd = *(const f32x4*)(f_dst + kt * 16 + g * 4);

            const char* lb = smem + buf * 32768 + (size_t)(ktl * 4) * 1024
                           + (size_t)lane * 16;
            const short8v b0 = *(const short8v*)(lb);
            const short8v b1 = *(const short8v*)(lb + 1024);
            const short8v b2 = *(const short8v*)(lb + 2048);
            const short8v b3 = *(const short8v*)(lb + 3072);

            const unsigned int sh = b16 >> (g * 4);
            float p[4];
            #pragma unroll
            for (int e = 0; e < 4; ++e) {
                float s = fsrc_r + fd[e];
                s = s > 0.f ? s : 0.2f * s;          // leaky_relu
                p[e] = (sh & (1u << e)) ? __expf(s) : 0.f;
            }
            psum += (p[0] + p[1]) + (p[2] + p[3]);
            const short4v af = { (short)bf16_bits(p[0]), (short)bf16_bits(p[1]),
                                 (short)bf16_bits(p[2]), (short)bf16_bits(p[3]) };

            acc[0] = mfma16(af, __builtin_shufflevector(b0, b0, 0, 1, 2, 3), acc[0]);
            acc[1] = mfma16(af, __builtin_shufflevector(b0, b0, 4, 5, 6, 7), acc[1]);
            acc[2] = mfma16(af, __builtin_shufflevector(b1, b1, 0, 1, 2, 3), acc[2]);
            acc[3] = mfma16(af, __builtin_shufflevector(b1, b1, 4, 5, 6, 7), acc[3]);
            acc[4] = mfma16(af, __builtin_shufflevector(b2, b2, 0, 1, 2, 3), acc[4]);
            acc[5] = mfma16(af, __builtin_shufflevector(b2, b2, 4, 5, 6, 7), acc[5]);
            acc[6] = mfma16(af, __builtin_shufflevector(b3, b3, 0, 1, 2, 3), acc[6]);
            acc[7] = mfma16(af, __builtin_shufflevector(b3, b3, 4, 5, 6, 7), acc[7]);
        }
        buf ^= 1;
    }

    // rowsum partials: reduce over the 4 g-groups; lanes 0-15 store direct
    psum += __shfl_xor(psum, 16, 64);
    psum += __shfl_xor(psum, 32, 64);
    if (lane < 16)
        rsPart[(size_t)ks * NN + rowbase + w * 16 + lane] = psum;

    __syncthreads();   // all waves done reading stage buffers

    // wave-private LDS transpose (frag -> row-major 16x128), then coalesced
    float* lt = (float*)(smem + w * 8192);   // 8 KiB per wave
    #pragma unroll
    for (int nf = 0; nf < 8; ++nf)
        #pragma unroll
        for (int q = 0; q < 4; ++q)
            lt[(4 * g + q) * OF + nf * 16 + r] = acc[nf][q];

    float* pb = part + ((size_t)ks * NN + rowbase + w * 16) * OF;
    #pragma unroll
    for (int j = 0; j < 8; ++j) {
        const int idx = j * 64 + lane;       // f32x4 index in 16x128 tile
        *(f32x4*)(pb + (size_t)idx * 4) = *(const f32x4*)&lt[idx * 4];
    }
}

// ---------------------------------------------------------------------------
// Finish: out = relu( (sum_ks part[ks]) / (sum_ks rs[ks]) ).
// ---------------------------------------------------------------------------
__global__ __launch_bounds__(512) void gat_finish(
    const float* __restrict__ part, const float* __restrict__ rsPart,
    float* __restrict__ out)
{
    const int tg  = blockIdx.x * 512 + threadIdx.x;   // f32x4 index
    const int row = tg >> 5;

    f32x4 v = {};
    float den = 0.f;
    #pragma unroll
    for (int ks = 0; ks < 8; ++ks) {
        v   += *(const f32x4*)(part + (size_t)ks * NN * OF + (size_t)tg * 4);
        den += rsPart[(size_t)ks * NN + row];
    }
    const float inv = 1.0f / den;
    f32x4 o = v * inv;
    #pragma unroll
    for (int e = 0; e < 4; ++e) o[e] = fmaxf(o[e], 0.f);
    *(f32x4*)(out + (size_t)tg * 4) = o;
}

extern "C" void kernel_launch(void* const* d_in, const int* in_sizes, int n_in,
                              void* d_out, int out_size, void* d_ws, size_t ws_size,
                              hipStream_t stream) {
    const float* X   = (const float*)d_in[0];
    const int*   adj = (const int*)d_in[1];
    const float* W   = (const float*)d_in[2];
    const float* a   = (const float*)d_in[3];
    float* out = (float*)d_out;

    char* ws = (char*)d_ws;
    unsigned short* HtB    = (unsigned short*)ws;                  // 2 MiB
    float*          f_src  = (float*)(ws + 2097152);               // 32 KiB
    float*          f_dst  = (float*)(ws + 2097152 + 32768);       // 32 KiB
    u64*            bits   = (u64*)(ws + 2162688);                 // 8 MiB
    float*          rsPart = (float*)(ws + 10551296);              // 256 KiB
    float*          part   = (float*)(ws + 10813440);              // 32 MiB

    gat_pack<<<NN / 4, 256, 0, stream>>>(adj, bits);
    gat_prep<<<NN / 32, 256, 0, stream>>>(X, W, a, HtB, f_src, f_dst);
    gat_row<<<512, 512, 0, stream>>>((const unsigned short*)bits, (const char*)HtB,
                                     f_src, f_dst, part, rsPart);
    gat_finish<<<512, 512, 0, stream>>>(part, rsPart, out);
}

// Round 15
// 103.214 us; speedup vs baseline: 2.1221x; 1.4657x over previous
//
#include <hip/hip_runtime.h>
#include <hip/hip_bf16.h>

#define NN 8192
#define IN_F 256
#define OF 128

typedef float  f32x4   __attribute__((ext_vector_type(4)));
typedef short  short4v __attribute__((ext_vector_type(4)));
typedef short  short8v __attribute__((ext_vector_type(8)));
typedef int    int4v   __attribute__((ext_vector_type(4)));
typedef __bf16 bf16x8v __attribute__((ext_vector_type(8)));

__device__ __forceinline__ unsigned short bf16_bits(float x) {
    __bf16 b = (__bf16)x;
    return __builtin_bit_cast(unsigned short, b);
}

// K=32 bf16 MFMA (gfx950): A row=lane&15, k=8*(lane>>4)+e; B col=lane&15,
// k=8*(lane>>4)+e; D col=lane&15, row=4*(lane>>4)+q  (m89-verified family).
__device__ __forceinline__ f32x4 mfma32(short8v a, short8v b, f32x4 c) {
#if __has_builtin(__builtin_amdgcn_mfma_f32_16x16x32_bf16)
    return __builtin_amdgcn_mfma_f32_16x16x32_bf16(
        __builtin_bit_cast(bf16x8v, a), __builtin_bit_cast(bf16x8v, b), c, 0, 0, 0);
#else
    asm("v_mfma_f32_16x16x32_bf16 %0, %1, %2, %0" : "+v"(c) : "v"(a), "v"(b));
    return c;
#endif
}

// async global->LDS, 16B per lane; LDS dest = wave-uniform base + lane*16
__device__ __forceinline__ void gload_lds16(const void* gsrc, void* lds) {
    __builtin_amdgcn_global_load_lds(
        (const __attribute__((address_space(1))) int*)gsrc,
        (__attribute__((address_space(3))) int*)lds, 16, 0, 0);
}

// ---------------------------------------------------------------------------
// Kernel A: h = X @ W (f32, LDS-staged W).  Emits HtB in K=32 B-fragment
// order: for h[j][f]:  kt=j>>5, g=(j>>3)&3, e=j&7, np=f>>4, c=f&15
//   short index = ((kt*8 + np)*64 + g*16 + c)*8 + e      (8 KB per kt)
// Also f_src = h.a[:OF], f_dst = h.a[OF:].
// ---------------------------------------------------------------------------
__global__ __launch_bounds__(256) void gat_prep(
    const float* __restrict__ X, const float* __restrict__ W,
    const float* __restrict__ a, unsigned short* __restrict__ HtB,
    float* __restrict__ f_src, float* __restrict__ f_dst)
{
    __shared__ float Wlds[IN_F * OF];   // 128 KiB
    __shared__ float red_s[32][8];
    __shared__ float red_d[32][8];

    const int t = threadIdx.x;
    {
        const f32x4* Wv = (const f32x4*)W;
        f32x4*       Wl = (f32x4*)Wlds;
        #pragma unroll
        for (int c = 0; c < 32; ++c) Wl[c * 256 + t] = Wv[c * 256 + t];
    }
    __syncthreads();

    const int row = t & 31;
    const int sub = t >> 5;            // feature block np = sub (16 feats)
    const int i   = blockIdx.x * 32 + row;

    f32x4 acc[4] = {};
    const float* xrow = X + (size_t)i * IN_F;

    #pragma unroll 4
    for (int kk = 0; kk < IN_F; kk += 4) {
        f32x4 xv = *(const f32x4*)(xrow + kk);
        #pragma unroll
        for (int e = 0; e < 4; ++e) {
            const f32x4* wr = (const f32x4*)(Wlds + (kk + e) * OF + sub * 16);
            float xs = xv[e];
            #pragma unroll
            for (int c4 = 0; c4 < 4; ++c4) acc[c4] += xs * wr[c4];
        }
    }

    const int kt = i >> 5;
    const int gq = (i >> 3) & 3;
    const int eq = i & 7;

    float ps = 0.f, pd = 0.f;
    #pragma unroll
    for (int c4 = 0; c4 < 4; ++c4) {
        #pragma unroll
        for (int e = 0; e < 4; ++e) {
            float v = acc[c4][e];
            int   c = c4 * 4 + e;      // 0..15 within feature block
            ps += v * a[sub * 16 + c];
            pd += v * a[OF + sub * 16 + c];
            HtB[(size_t)(((kt * 8 + sub) * 64) + gq * 16 + c) * 8 + eq]
                = bf16_bits(v);
        }
    }
    red_s[row][sub] = ps;
    red_d[row][sub] = pd;
    __syncthreads();
    if (t < 32) {
        float s = 0.f;
        #pragma unroll
        for (int s8 = 0; s8 < 8; ++s8) s += red_s[t][s8];
        f_src[blockIdx.x * 32 + t] = s;
    } else if (t < 64) {
        const int r2 = t - 32;
        float s = 0.f;
        #pragma unroll
        for (int s8 = 0; s8 < 8; ++s8) s += red_d[r2][s8];
        f_dst[blockIdx.x * 32 + r2] = s;
    }
}

// ---------------------------------------------------------------------------
// gat_row2 (v14b): K=32 MFMA + row-owning waves + block-shared staged B.
// Grid = 64 row-blocks x 8 k-splits = 512 blocks (2/CU) x 512 threads.
// Block = 128 rows; wave w owns rows rowbase+w*16..+15.  K-range =
// ks*1024..+1023 = 32 kt32 tiles; 8 supersteps x 4 kt32.  B slab (32 KB =
// 4 kt32) staged via global_load_lds, double-buffered, shared by all waves.
// Per iter/wave: 2 adj int4 (full 128B row-segments) + 2 f_dst f32x4 +
// 8 ds_read_b128 + 8 exp + 8 MFMA(16x16x32)  -- 32 iterations total.
// Partials (16x128 f32/wave) + rowsums to ws; finish combines 8 k-splits.
// ---------------------------------------------------------------------------
__global__ __launch_bounds__(512, 4) void gat_row2(
    const int* __restrict__ adj, const char* __restrict__ htb,
    const float* __restrict__ f_src, const float* __restrict__ f_dst,
    float* __restrict__ part, float* __restrict__ rsPart)
{
    __shared__ __align__(16) char smem[65536];   // 2 x 32KiB dbuf; epilogue lt

    const int tid  = threadIdx.x;
    const int w    = tid >> 6;
    const int lane = tid & 63;
    const int r    = lane & 15;
    const int g    = lane >> 4;
    const int ms   = blockIdx.x >> 3;
    const int ks   = blockIdx.x & 7;
    const int rowbase = ms * 128;
    const int row  = rowbase + w * 16 + r;

    const float fsrc_r = f_src[row];
    const int*   aptr = adj + (size_t)row * NN + ks * 1024 + g * 8;
    const float* fptr = f_dst + ks * 1024 + g * 8;
    const char*  gB   = htb + (size_t)ks * 32 * 8192;   // 8 KB per kt32

    f32x4 acc[8] = {};
    float psum = 0.f;

    // prologue: stage superstep 0 into buf 0 (32 KB, linear)
    #pragma unroll
    for (int u = 0; u < 4; ++u)
        gload_lds16(gB + (size_t)(u * 512 + tid) * 16,
                    smem + (size_t)(u * 512 + tid) * 16);

    int buf = 0;
    for (int ss = 0; ss < 8; ++ss) {
        __syncthreads();   // stage(ss) resident (vmcnt drain); buf^1 free

        if (ss + 1 < 8) {
            const char* gs = gB + (size_t)(ss + 1) * 32768;
            #pragma unroll
            for (int u = 0; u < 4; ++u)
                gload_lds16(gs + (size_t)(u * 512 + tid) * 16,
                            smem + (buf ^ 1) * 32768 + (size_t)(u * 512 + tid) * 16);
        }

        #pragma unroll
        for (int ktl = 0; ktl < 4; ++ktl) {
            const int i = ss * 4 + ktl;          // kt32 local index 0..31

            // adj: 8 ints for this lane's (row r, cols g*8..+7)
            const int4v a0 = *(const int4v*)(aptr + i * 32);
            const int4v a1 = *(const int4v*)(aptr + i * 32 + 4);
            const f32x4 fd0 = *(const f32x4*)(fptr + i * 32);
            const f32x4 fd1 = *(const f32x4*)(fptr + i * 32 + 4);

            // B fragments: 8 x ds_read_b128 from the staged slab
            const char* lb = smem + buf * 32768 + ktl * 8192 + (size_t)lane * 16;
            short8v bv[8];
            #pragma unroll
            for (int np = 0; np < 8; ++np)
                bv[np] = *(const short8v*)(lb + np * 1024);

            float p[8];
            #pragma unroll
            for (int e = 0; e < 4; ++e) {
                float s0 = fsrc_r + fd0[e];
                s0 = s0 > 0.f ? s0 : 0.2f * s0;      // leaky_relu
                p[e] = (a0[e] != 0) ? __expf(s0) : 0.f;
                float s1 = fsrc_r + fd1[e];
                s1 = s1 > 0.f ? s1 : 0.2f * s1;
                p[4 + e] = (a1[e] != 0) ? __expf(s1) : 0.f;
            }
            psum += ((p[0] + p[1]) + (p[2] + p[3]))
                  + ((p[4] + p[5]) + (p[6] + p[7]));
            const short8v af = { (short)bf16_bits(p[0]), (short)bf16_bits(p[1]),
                                 (short)bf16_bits(p[2]), (short)bf16_bits(p[3]),
                                 (short)bf16_bits(p[4]), (short)bf16_bits(p[5]),
                                 (short)bf16_bits(p[6]), (short)bf16_bits(p[7]) };

            #pragma unroll
            for (int np = 0; np < 8; ++np)
                acc[np] = mfma32(af, bv[np], acc[np]);
        }
        buf ^= 1;
    }

    // rowsum partials: reduce over the 4 g-groups; lanes 0-15 store direct
    psum += __shfl_xor(psum, 16, 64);
    psum += __shfl_xor(psum, 32, 64);
    if (lane < 16)
        rsPart[(size_t)ks * NN + rowbase + w * 16 + lane] = psum;

    __syncthreads();   // all waves done reading stage buffers

    // wave-private LDS transpose (frag -> row-major 16x128), then coalesced
    float* lt = (float*)(smem + w * 8192);   // 8 KiB per wave
    #pragma unroll
    for (int np = 0; np < 8; ++np)
        #pragma unroll
        for (int q = 0; q < 4; ++q)
            lt[(4 * g + q) * OF + np * 16 + r] = acc[np][q];

    float* pb = part + ((size_t)ks * NN + rowbase + w * 16) * OF;
    #pragma unroll
    for (int j = 0; j < 8; ++j) {
        const int idx = j * 64 + lane;       // f32x4 index in 16x128 tile
        *(f32x4*)(pb + (size_t)idx * 4) = *(const f32x4*)&lt[idx * 4];
    }
}

// ---------------------------------------------------------------------------
// Finish: out = relu( (sum_ks part[ks]) / (sum_ks rs[ks]) ).
// ---------------------------------------------------------------------------
__global__ __launch_bounds__(512) void gat_finish(
    const float* __restrict__ part, const float* __restrict__ rsPart,
    float* __restrict__ out)
{
    const int tg  = blockIdx.x * 512 + threadIdx.x;   // f32x4 index
    const int row = tg >> 5;

    f32x4 v = {};
    float den = 0.f;
    #pragma unroll
    for (int ks = 0; ks < 8; ++ks) {
        v   += *(const f32x4*)(part + (size_t)ks * NN * OF + (size_t)tg * 4);
        den += rsPart[(size_t)ks * NN + row];
    }
    const float inv = 1.0f / den;
    f32x4 o = v * inv;
    #pragma unroll
    for (int e = 0; e < 4; ++e) o[e] = fmaxf(o[e], 0.f);
    *(f32x4*)(out + (size_t)tg * 4) = o;
}

extern "C" void kernel_launch(void* const* d_in, const int* in_sizes, int n_in,
                              void* d_out, int out_size, void* d_ws, size_t ws_size,
                              hipStream_t stream) {
    const float* X   = (const float*)d_in[0];
    const int*   adj = (const int*)d_in[1];
    const float* W   = (const float*)d_in[2];
    const float* a   = (const float*)d_in[3];
    float* out = (float*)d_out;

    char* ws = (char*)d_ws;
    unsigned short* HtB    = (unsigned short*)ws;                  // 2 MiB
    float*          f_src  = (float*)(ws + 2097152);               // 32 KiB
    float*          f_dst  = (float*)(ws + 2097152 + 32768);       // 32 KiB
    float*          rsPart = (float*)(ws + 2162688);               // 256 KiB
    float*          part   = (float*)(ws + 2424832);               // 32 MiB

    gat_prep<<<NN / 32, 256, 0, stream>>>(X, W, a, HtB, f_src, f_dst);
    gat_row2<<<512, 512, 0, stream>>>(adj, (const char*)HtB,
                                      f_src, f_dst, part, rsPart);
    gat_finish<<<512, 512, 0, stream>>>(part, rsPart, out);
}

// Round 16
// 101.680 us; speedup vs baseline: 2.1542x; 1.0151x over previous
//
#include <hip/hip_runtime.h>
#include <hip/hip_bf16.h>

#define NN 8192
#define IN_F 256
#define OF 128

typedef float  f32x4   __attribute__((ext_vector_type(4)));
typedef short  short4v __attribute__((ext_vector_type(4)));
typedef short  short8v __attribute__((ext_vector_type(8)));
typedef int    int4v   __attribute__((ext_vector_type(4)));
typedef __bf16 bf16x8v __attribute__((ext_vector_type(8)));

__device__ __forceinline__ unsigned short bf16_bits(float x) {
    __bf16 b = (__bf16)x;
    return __builtin_bit_cast(unsigned short, b);
}

// K=32 bf16 MFMA (gfx950): A row=lane&15, k=8*(lane>>4)+e; B col=lane&15,
// k=8*(lane>>4)+e; D col=lane&15, row=4*(lane>>4)+q  (m89-verified family).
__device__ __forceinline__ f32x4 mfma32(short8v a, short8v b, f32x4 c) {
#if __has_builtin(__builtin_amdgcn_mfma_f32_16x16x32_bf16)
    return __builtin_amdgcn_mfma_f32_16x16x32_bf16(
        __builtin_bit_cast(bf16x8v, a), __builtin_bit_cast(bf16x8v, b), c, 0, 0, 0);
#else
    asm("v_mfma_f32_16x16x32_bf16 %0, %1, %2, %0" : "+v"(c) : "v"(a), "v"(b));
    return c;
#endif
}

// async global->LDS, 16B per lane; LDS dest = wave-uniform base + lane*16
__device__ __forceinline__ void gload_lds16(const void* gsrc, void* lds) {
    __builtin_amdgcn_global_load_lds(
        (const __attribute__((address_space(1))) int*)gsrc,
        (__attribute__((address_space(3))) int*)lds, 16, 0, 0);
}

// ---------------------------------------------------------------------------
// Kernel A: h = X @ W (f32, LDS-staged W).  Emits HtB in K=32 B-fragment
// order: for h[j][f]:  kt=j>>5, g=(j>>3)&3, e=j&7, np=f>>4, c=f&15
//   short index = ((kt*8 + np)*64 + g*16 + c)*8 + e      (8 KB per kt)
// Also f_src = h.a[:OF], f_dst = h.a[OF:].
// ---------------------------------------------------------------------------
__global__ __launch_bounds__(256) void gat_prep(
    const float* __restrict__ X, const float* __restrict__ W,
    const float* __restrict__ a, unsigned short* __restrict__ HtB,
    float* __restrict__ f_src, float* __restrict__ f_dst)
{
    __shared__ float Wlds[IN_F * OF];   // 128 KiB
    __shared__ float red_s[32][8];
    __shared__ float red_d[32][8];

    const int t = threadIdx.x;
    {
        const f32x4* Wv = (const f32x4*)W;
        f32x4*       Wl = (f32x4*)Wlds;
        #pragma unroll
        for (int c = 0; c < 32; ++c) Wl[c * 256 + t] = Wv[c * 256 + t];
    }
    __syncthreads();

    const int row = t & 31;
    const int sub = t >> 5;            // feature block np = sub (16 feats)
    const int i   = blockIdx.x * 32 + row;

    f32x4 acc[4] = {};
    const float* xrow = X + (size_t)i * IN_F;

    #pragma unroll 4
    for (int kk = 0; kk < IN_F; kk += 4) {
        f32x4 xv = *(const f32x4*)(xrow + kk);
        #pragma unroll
        for (int e = 0; e < 4; ++e) {
            const f32x4* wr = (const f32x4*)(Wlds + (kk + e) * OF + sub * 16);
            float xs = xv[e];
            #pragma unroll
            for (int c4 = 0; c4 < 4; ++c4) acc[c4] += xs * wr[c4];
        }
    }

    const int kt = i >> 5;
    const int gq = (i >> 3) & 3;
    const int eq = i & 7;

    float ps = 0.f, pd = 0.f;
    #pragma unroll
    for (int c4 = 0; c4 < 4; ++c4) {
        #pragma unroll
        for (int e = 0; e < 4; ++e) {
            float v = acc[c4][e];
            int   c = c4 * 4 + e;      // 0..15 within feature block
            ps += v * a[sub * 16 + c];
            pd += v * a[OF + sub * 16 + c];
            HtB[(size_t)(((kt * 8 + sub) * 64) + gq * 16 + c) * 8 + eq]
                = bf16_bits(v);
        }
    }
    red_s[row][sub] = ps;
    red_d[row][sub] = pd;
    __syncthreads();
    if (t < 32) {
        float s = 0.f;
        #pragma unroll
        for (int s8 = 0; s8 < 8; ++s8) s += red_s[t][s8];
        f_src[blockIdx.x * 32 + t] = s;
    } else if (t < 64) {
        const int r2 = t - 32;
        float s = 0.f;
        #pragma unroll
        for (int s8 = 0; s8 < 8; ++s8) s += red_d[r2][s8];
        f_dst[blockIdx.x * 32 + r2] = s;
    }
}

// ---------------------------------------------------------------------------
// gat_row3 (v16): 2 A-fragments per wave -> every B ds_read feeds 16 MFMAs.
// Grid = 32 row-blocks x 8 k-splits = 256 blocks (1/CU) x 512 threads.
// Block = 256 rows; wave w owns rows rowbase+w*32..+31 (two 16-row groups).
// K-range = ks*1024..+1023 = 32 kt32; 4 supersteps x 8 kt32 (64 KB slab,
// double-buffered, 128 KiB LDS) -> 4 barrier drains, huge straight-line
// regions.  Per kt32/wave: 4 adj int4 (full 128B segments) + 2 f_dst +
// 8 ds_read_b128 (shared by both row groups) + 16 exp + 16 MFMA(16x16x32).
// Partials + rowsums to ws; finish combines 8 k-splits.
// ---------------------------------------------------------------------------
__global__ __launch_bounds__(512, 2) void gat_row3(
    const int* __restrict__ adj, const char* __restrict__ htb,
    const float* __restrict__ f_src, const float* __restrict__ f_dst,
    float* __restrict__ part, float* __restrict__ rsPart)
{
    __shared__ __align__(16) char smem[131072];   // 2 x 64KiB dbuf; epilogue lt

    const int tid  = threadIdx.x;
    const int w    = tid >> 6;
    const int lane = tid & 63;
    const int r    = lane & 15;
    const int g    = lane >> 4;
    const int ms   = blockIdx.x >> 3;
    const int ks   = blockIdx.x & 7;
    const int rowbase = ms * 256;
    const int row0 = rowbase + w * 32 + r;
    const int row1 = row0 + 16;

    const float fsrc0 = f_src[row0];
    const float fsrc1 = f_src[row1];
    const int*   aptr0 = adj + (size_t)row0 * NN + ks * 1024 + g * 8;
    const int*   aptr1 = adj + (size_t)row1 * NN + ks * 1024 + g * 8;
    const float* fptr  = f_dst + ks * 1024 + g * 8;
    const char*  gB    = htb + (size_t)ks * 262144;   // 32 kt32 x 8 KB

    f32x4 acc0[8] = {};
    f32x4 acc1[8] = {};
    float psum0 = 0.f, psum1 = 0.f;

    // prologue: stage superstep 0 into buf 0 (64 KB, linear; 8 x 16B/thread)
    #pragma unroll
    for (int u = 0; u < 8; ++u)
        gload_lds16(gB + (size_t)(u * 512 + tid) * 16,
                    smem + (size_t)(u * 512 + tid) * 16);

    int buf = 0;
    for (int ss = 0; ss < 4; ++ss) {
        __syncthreads();   // stage(ss) resident (vmcnt drain); buf^1 free

        if (ss + 1 < 4) {
            const char* gs = gB + (size_t)(ss + 1) * 65536;
            #pragma unroll
            for (int u = 0; u < 8; ++u)
                gload_lds16(gs + (size_t)(u * 512 + tid) * 16,
                            smem + (buf ^ 1) * 65536 + (size_t)(u * 512 + tid) * 16);
        }

        #pragma unroll
        for (int ktl = 0; ktl < 8; ++ktl) {
            const int i = ss * 8 + ktl;          // kt32 local index 0..31

            const int4v a0 = *(const int4v*)(aptr0 + i * 32);
            const int4v a1 = *(const int4v*)(aptr0 + i * 32 + 4);
            const int4v a2 = *(const int4v*)(aptr1 + i * 32);
            const int4v a3 = *(const int4v*)(aptr1 + i * 32 + 4);
            const f32x4 fd0 = *(const f32x4*)(fptr + i * 32);
            const f32x4 fd1 = *(const f32x4*)(fptr + i * 32 + 4);

            const char* lb = smem + buf * 65536 + ktl * 8192 + (size_t)lane * 16;
            short8v bv[8];
            #pragma unroll
            for (int np = 0; np < 8; ++np)
                bv[np] = *(const short8v*)(lb + np * 1024);

            float p0[8], p1[8];
            #pragma unroll
            for (int e = 0; e < 4; ++e) {
                float s;
                s = fsrc0 + fd0[e]; s = s > 0.f ? s : 0.2f * s;
                p0[e]     = (a0[e] != 0) ? __expf(s) : 0.f;
                s = fsrc0 + fd1[e]; s = s > 0.f ? s : 0.2f * s;
                p0[4 + e] = (a1[e] != 0) ? __expf(s) : 0.f;
                s = fsrc1 + fd0[e]; s = s > 0.f ? s : 0.2f * s;
                p1[e]     = (a2[e] != 0) ? __expf(s) : 0.f;
                s = fsrc1 + fd1[e]; s = s > 0.f ? s : 0.2f * s;
                p1[4 + e] = (a3[e] != 0) ? __expf(s) : 0.f;
            }
            psum0 += ((p0[0] + p0[1]) + (p0[2] + p0[3]))
                   + ((p0[4] + p0[5]) + (p0[6] + p0[7]));
            psum1 += ((p1[0] + p1[1]) + (p1[2] + p1[3]))
                   + ((p1[4] + p1[5]) + (p1[6] + p1[7]));
            const short8v af0 = { (short)bf16_bits(p0[0]), (short)bf16_bits(p0[1]),
                                  (short)bf16_bits(p0[2]), (short)bf16_bits(p0[3]),
                                  (short)bf16_bits(p0[4]), (short)bf16_bits(p0[5]),
                                  (short)bf16_bits(p0[6]), (short)bf16_bits(p0[7]) };
            const short8v af1 = { (short)bf16_bits(p1[0]), (short)bf16_bits(p1[1]),
                                  (short)bf16_bits(p1[2]), (short)bf16_bits(p1[3]),
                                  (short)bf16_bits(p1[4]), (short)bf16_bits(p1[5]),
                                  (short)bf16_bits(p1[6]), (short)bf16_bits(p1[7]) };

            #pragma unroll
            for (int np = 0; np < 8; ++np) {
                acc0[np] = mfma32(af0, bv[np], acc0[np]);
                acc1[np] = mfma32(af1, bv[np], acc1[np]);
            }
        }
        buf ^= 1;
    }

    // rowsum partials: reduce over the 4 g-groups; lanes 0-15 store direct
    psum0 += __shfl_xor(psum0, 16, 64);
    psum0 += __shfl_xor(psum0, 32, 64);
    psum1 += __shfl_xor(psum1, 16, 64);
    psum1 += __shfl_xor(psum1, 32, 64);
    if (lane < 16) {
        rsPart[(size_t)ks * NN + rowbase + w * 32 + lane]      = psum0;
        rsPart[(size_t)ks * NN + rowbase + w * 32 + 16 + lane] = psum1;
    }

    __syncthreads();   // all waves done reading stage buffers

    // wave-private LDS transpose (frag -> row-major 32x128), then coalesced
    float* lt = (float*)(smem + w * 16384);   // 16 KiB per wave
    #pragma unroll
    for (int np = 0; np < 8; ++np)
        #pragma unroll
        for (int q = 0; q < 4; ++q) {
            lt[(4 * g + q) * OF + np * 16 + r]        = acc0[np][q];
            lt[2048 + (4 * g + q) * OF + np * 16 + r] = acc1[np][q];
        }

    float* pb = part + ((size_t)ks * NN + rowbase + w * 32) * OF;
    #pragma unroll
    for (int j = 0; j < 16; ++j) {
        const int idx = j * 64 + lane;       // f32x4 index in 32x128 tile
        *(f32x4*)(pb + (size_t)idx * 4) = *(const f32x4*)&lt[idx * 4];
    }
}

// ---------------------------------------------------------------------------
// Finish: out = relu( (sum_ks part[ks]) / (sum_ks rs[ks]) ).
// ---------------------------------------------------------------------------
__global__ __launch_bounds__(512) void gat_finish(
    const float* __restrict__ part, const float* __restrict__ rsPart,
    float* __restrict__ out)
{
    const int tg  = blockIdx.x * 512 + threadIdx.x;   // f32x4 index
    const int row = tg >> 5;

    f32x4 v = {};
    float den = 0.f;
    #pragma unroll
    for (int ks = 0; ks < 8; ++ks) {
        v   += *(const f32x4*)(part + (size_t)ks * NN * OF + (size_t)tg * 4);
        den += rsPart[(size_t)ks * NN + row];
    }
    const float inv = 1.0f / den;
    f32x4 o = v * inv;
    #pragma unroll
    for (int e = 0; e < 4; ++e) o[e] = fmaxf(o[e], 0.f);
    *(f32x4*)(out + (size_t)tg * 4) = o;
}

extern "C" void kernel_launch(void* const* d_in, const int* in_sizes, int n_in,
                              void* d_out, int out_size, void* d_ws, size_t ws_size,
                              hipStream_t stream) {
    const float* X   = (const float*)d_in[0];
    const int*   adj = (const int*)d_in[1];
    const float* W   = (const float*)d_in[2];
    const float* a   = (const float*)d_in[3];
    float* out = (float*)d_out;

    char* ws = (char*)d_ws;
    unsigned short* HtB    = (unsigned short*)ws;                  // 2 MiB
    float*          f_src  = (float*)(ws + 2097152);               // 32 KiB
    float*          f_dst  = (float*)(ws + 2097152 + 32768);       // 32 KiB
    float*          rsPart = (float*)(ws + 2162688);               // 256 KiB
    float*          part   = (float*)(ws + 2424832);               // 32 MiB

    gat_prep<<<NN / 32, 256, 0, stream>>>(X, W, a, HtB, f_src, f_dst);
    gat_row3<<<256, 512, 0, stream>>>(adj, (const char*)HtB,
                                      f_src, f_dst, part, rsPart);
    gat_finish<<<512, 512, 0, stream>>>(part, rsPart, out);
}